// Round 1
// baseline (1272.696 us; speedup 1.0000x reference)
//
#include <hip/hip_runtime.h>

// Problem constants (fixed by setup_inputs)
#define NB 4
#define NS 8192
#define NH 16
#define ND 64
#define NW 128
#define NC 64          // NS / NW
#define NE 384         // 3 * NW

typedef __attribute__((ext_vector_type(8))) short short8;
typedef __attribute__((ext_vector_type(4))) float f32x4;

// LDS row strides (bf16 elements), padded to break bank-conflict strides
#define QSTR 72        // 64 + 8
#define VSTR 136       // 128 + 8
#define PSTR 40        // 32 + 8

__device__ __forceinline__ unsigned short f2bf(float f) {
    unsigned int u = __float_as_uint(f);
    u += 0x7fffu + ((u >> 16) & 1u);      // round-to-nearest-even
    return (unsigned short)(u >> 16);
}
__device__ __forceinline__ float bf2f(unsigned short h) {
    return __uint_as_float(((unsigned int)h) << 16);
}

__global__ __launch_bounds__(512, 2) void swa_fused(
    const float* __restrict__ qg, const float* __restrict__ kg,
    const float* __restrict__ vg, float* __restrict__ outg,
    float* __restrict__ attng)
{
    __shared__ unsigned short sQh[NW * QSTR];   // Q hi (bf16)
    __shared__ unsigned short sQl[NW * QSTR];   // Q lo
    __shared__ unsigned short sB1[NW * QSTR];   // K hi, later V^T (64 x VSTR fits)
    __shared__ unsigned short sB2[NW * QSTR];   // K lo
    __shared__ unsigned short sP[8 * 16 * PSTR];// per-wave P layout scratch

    const int tid  = threadIdx.x;
    const int lane = tid & 63;
    const int wv   = tid >> 6;        // wave 0..7 -> query rows wv*16..wv*16+15
    const int m    = lane & 15;
    const int quad = lane >> 4;

    const int bid = blockIdx.x;
    const int c = bid & (NC - 1);
    const int h = (bid >> 6) & (NH - 1);
    const int b = bid >> 10;

    const int rs = NH * ND;           // 1024 floats per s-step
    const size_t bh_off = ((size_t)b * NS) * rs + (size_t)h * ND;

    float4 pf[4];                     // register prefetch of one 128x64 tile

    auto load_tile = [&](const float* src, int cc) {
        const bool oob = (cc < 0) || (cc >= NC);
        #pragma unroll
        for (int i = 0; i < 4; ++i) {
            if (oob) {
                pf[i] = make_float4(0.f, 0.f, 0.f, 0.f);
            } else {
                int f  = tid + i * 512;            // float4 index in tile
                int r  = f >> 4;                   // row 0..127
                int c4 = (f & 15) << 2;            // col 0..60
                pf[i] = *(const float4*)(src + bh_off +
                         (size_t)(cc * NW + r) * rs + c4);
            }
        }
    };
    auto write_hl = [&](unsigned short* dh, unsigned short* dl) {
        #pragma unroll
        for (int i = 0; i < 4; ++i) {
            int f  = tid + i * 512;
            int r  = f >> 4;
            int c4 = (f & 15) << 2;
            float fv[4] = {pf[i].x, pf[i].y, pf[i].z, pf[i].w};
            unsigned short hh[4], ll[4];
            #pragma unroll
            for (int j = 0; j < 4; ++j) {
                hh[j] = f2bf(fv[j]);
                ll[j] = f2bf(fv[j] - bf2f(hh[j]));
            }
            uint2 ph, pl;
            ph.x = (unsigned)hh[0] | ((unsigned)hh[1] << 16);
            ph.y = (unsigned)hh[2] | ((unsigned)hh[3] << 16);
            pl.x = (unsigned)ll[0] | ((unsigned)ll[1] << 16);
            pl.y = (unsigned)ll[2] | ((unsigned)ll[3] << 16);
            *(uint2*)&dh[r * QSTR + c4] = ph;
            *(uint2*)&dl[r * QSTR + c4] = pl;
        }
    };
    auto write_vt = [&]() {   // transposed V^T[d][kpos] into sB1
        #pragma unroll
        for (int i = 0; i < 4; ++i) {
            int f  = tid + i * 512;
            int r  = f >> 4;
            int c4 = (f & 15) << 2;
            float fv[4] = {pf[i].x, pf[i].y, pf[i].z, pf[i].w};
            #pragma unroll
            for (int j = 0; j < 4; ++j)
                sB1[(c4 + j) * VSTR + r] = f2bf(fv[j]);
        }
    };

    // ---------------- Phase 1: stage Q and first K chunk ----------------
    load_tile(qg, c);
    write_hl(sQh, sQl);
    load_tile(kg, c - 1);
    write_hl(sB1, sB2);
    __syncthreads();

    // A-fragments of Q (persist whole kernel): A[m][k], k = quad*8+j
    short8 aQh[2], aQl[2];
    #pragma unroll
    for (int ks = 0; ks < 2; ++ks) {
        int off = (wv * 16 + m) * QSTR + ks * 32 + quad * 8;
        aQh[ks] = *(const short8*)&sQh[off];
        aQl[ks] = *(const short8*)&sQl[off];
    }

    load_tile(kg, c);   // prefetch self chunk

    // ---------------- Phase 2: scores, hi/lo split (near-fp32) ----------
    f32x4 sc[24];       // [e*8 + t], 16x16 C-layout tiles
    #pragma unroll
    for (int e = 0; e < 3; ++e) {
        #pragma unroll
        for (int t = 0; t < 8; ++t) {
            f32x4 acc = {0.f, 0.f, 0.f, 0.f};
            #pragma unroll
            for (int ks = 0; ks < 2; ++ks) {
                int off = (t * 16 + m) * QSTR + ks * 32 + quad * 8;
                short8 bh = *(const short8*)&sB1[off];
                short8 bl = *(const short8*)&sB2[off];
                acc = __builtin_amdgcn_mfma_f32_16x16x32_bf16(aQh[ks], bh, acc, 0, 0, 0);
                acc = __builtin_amdgcn_mfma_f32_16x16x32_bf16(aQl[ks], bh, acc, 0, 0, 0);
                acc = __builtin_amdgcn_mfma_f32_16x16x32_bf16(aQh[ks], bl, acc, 0, 0, 0);
            }
            sc[e * 8 + t] = acc;
        }
        __syncthreads();                         // done reading K_e
        if (e < 2) {
            write_hl(sB1, sB2);                  // commit prefetched K
            __syncthreads();
            if (e == 0) load_tile(kg, c + 1);    // prefetch next K
            else        load_tile(vg, c - 1);    // prefetch first V
        }
    }

    // ---------------- Phase 3: softmax over 384 (fp32) -------------------
    #pragma unroll
    for (int r = 0; r < 4; ++r) {
        float mval = sc[0][r];
        #pragma unroll
        for (int i = 1; i < 24; ++i) mval = fmaxf(mval, sc[i][r]);
        #pragma unroll
        for (int d = 1; d < 16; d <<= 1)
            mval = fmaxf(mval, __shfl_xor(mval, d, 16));
        float s = 0.f;
        #pragma unroll
        for (int i = 0; i < 24; ++i) {
            float p = __expf(sc[i][r] - mval);
            sc[i][r] = p;
            s += p;
        }
        #pragma unroll
        for (int d = 1; d < 16; d <<= 1)
            s += __shfl_xor(s, d, 16);
        float inv = 1.0f / s;
        #pragma unroll
        for (int i = 0; i < 24; ++i) sc[i][r] *= inv;
    }

    // ---------------- Phase 4: write attn probs (fp32, nontemporal) ------
    {
        const size_t ab = ((size_t)b * NS) * (NH * NE) + (size_t)h * NE;
        #pragma unroll
        for (int i = 0; i < 24; ++i) {
            int e = i >> 3, t = i & 7;
            int col = e * NW + t * 16 + m;
            #pragma unroll
            for (int r = 0; r < 4; ++r) {
                int sg = c * NW + wv * 16 + quad * 4 + r;
                __builtin_nontemporal_store(sc[i][r],
                    attng + ab + (size_t)sg * (NH * NE) + col);
            }
        }
    }

    // ---------------- Phase 5: O = P @ V (bf16 MFMA) ----------------------
    f32x4 o[4];
    #pragma unroll
    for (int t = 0; t < 4; ++t) o[t] = (f32x4){0.f, 0.f, 0.f, 0.f};

    unsigned short* myP = sP + wv * 16 * PSTR;

    #pragma unroll
    for (int e = 0; e < 3; ++e) {
        write_vt();                  // commit prefetched V chunk (c-1+e)
        __syncthreads();
        if (e < 2) load_tile(vg, c + e);   // prefetch next V
        #pragma unroll
        for (int s4 = 0; s4 < 4; ++s4) {   // k-slices of 32 key positions
            // C-layout -> A-layout via wave-private LDS scratch (bf16)
            #pragma unroll
            for (int tt = 0; tt < 2; ++tt) {
                int t = s4 * 2 + tt;
                #pragma unroll
                for (int r = 0; r < 4; ++r)
                    myP[(quad * 4 + r) * PSTR + tt * 16 + m] =
                        f2bf(sc[e * 8 + t][r]);
            }
            __builtin_amdgcn_s_waitcnt(0xC07F);   // lgkmcnt(0), wave-local RAW
            short8 ap = *(const short8*)&myP[m * PSTR + quad * 8];
            #pragma unroll
            for (int t = 0; t < 4; ++t) {
                short8 bv = *(const short8*)&sB1[(t * 16 + m) * VSTR +
                                                 s4 * 32 + quad * 8];
                o[t] = __builtin_amdgcn_mfma_f32_16x16x32_bf16(ap, bv, o[t], 0, 0, 0);
            }
        }
        __syncthreads();             // done reading V_e before next write_vt
    }

    // ---------------- Phase 6: write out -----------------------------------
    #pragma unroll
    for (int t = 0; t < 4; ++t) {
        #pragma unroll
        for (int r = 0; r < 4; ++r) {
            int sg = c * NW + wv * 16 + quad * 4 + r;
            __builtin_nontemporal_store(o[t][r],
                outg + bh_off + (size_t)sg * rs + t * 16 + m);
        }
    }
}

extern "C" void kernel_launch(void* const* d_in, const int* in_sizes, int n_in,
                              void* d_out, int out_size, void* d_ws, size_t ws_size,
                              hipStream_t stream) {
    const float* q = (const float*)d_in[0];
    const float* k = (const float*)d_in[1];
    const float* v = (const float*)d_in[2];
    float* out  = (float*)d_out;                       // [4,8192,16,64]
    float* attn = out + (size_t)NB * NS * NH * ND;     // [4,8192,16,384]

    dim3 grid(NB * NH * NC);   // 4096 blocks, c fastest for K/V L2 reuse
    dim3 block(512);
    swa_fused<<<grid, block, 0, stream>>>(q, k, v, out, attn);
}